// Round 6
// baseline (363.680 us; speedup 1.0000x reference)
//
#include <hip/hip_runtime.h>
#include <math.h>

#define NAG 16
#define OBSD 128
#define STATED 256
#define ALPHA 0.2f
#define NEGV -9.0e15f
#define BTOT 8192
#define SLOT_H 3072   // halves per wave slot

typedef _Float16 v4h __attribute__((ext_vector_type(4)));
typedef _Float16 v8h __attribute__((ext_vector_type(8)));
typedef float v4f __attribute__((ext_vector_type(4)));

__device__ __forceinline__ float lrelu(float x){ return x > 0.f ? x : ALPHA*x; }
__device__ __forceinline__ float eluf(float x){ return x > 0.f ? x : (__expf(x)-1.f); }

#define MFMA16(A,B,C) __builtin_amdgcn_mfma_f32_16x16x16f16((A),(B),(C),0,0,0)
#define MFMA32(A,B,C) __builtin_amdgcn_mfma_f32_16x16x32_f16((A),(B),(C),0,0,0)

// ---- prep2: wa[4][128] = Wout @ aout halves (g1 u/v, gf u/v) ----
__global__ void prep2_kernel(const float* __restrict__ g1_Wout, const float* __restrict__ g1_aout,
                             const float* __restrict__ gf_Wout, const float* __restrict__ gf_aout,
                             float* __restrict__ wa){
  int k = threadIdx.x;  // 128
  float su = 0.f, sv = 0.f;
  for (int c = 0; c < 512; ++c){
    float w = g1_Wout[k*512 + c];
    su += w * g1_aout[c];
    sv += w * g1_aout[512 + c];
  }
  wa[k] = su; wa[128 + k] = sv;
  float fu = 0.f, fv = 0.f;
  for (int c = 0; c < 32; ++c){
    float w = gf_Wout[k*32 + c];
    fu += w * gf_aout[c];
    fv += w * gf_aout[32 + c];
  }
  wa[256 + k] = fu; wa[384 + k] = fv;
}

// ---- pack first-layer weights + (W@a) u/v columns: whf [17][4][64][8] ----
__global__ void pack_wh_kernel(const float* __restrict__ g1_Wh, const float* __restrict__ gf_Wh,
                               const float* __restrict__ g1_ah, const float* __restrict__ gf_ah,
                               _Float16* __restrict__ dst){
  int idx = blockIdx.x*256 + threadIdx.x;   // 34816 total
  if (idx >= 17*2048) return;
  int j = idx & 7, lane = (idx>>3)&63, kk = (idx>>9)&3, nt = idx>>11;
  int k = kk*32 + (lane>>4)*8 + j;
  int li = lane & 15;
  float v;
  if (nt < 16){
    int g = nt>>1, c = (nt&1)*16 + li;
    v = (g<4) ? g1_Wh[(g*OBSD + k)*32 + c] : gf_Wh[((g-4)*OBSD + k)*32 + c];
  } else {
    int g = li>>1, half = li&1;
    const float* W = (g<4)? (g1_Wh + g*OBSD*32) : (gf_Wh + (g-4)*OBSD*32);
    const float* a = ((g<4)? (g1_ah + g*64) : (gf_ah + (g-4)*64)) + half*32;
    float s = 0.f;
    for (int c=0;c<32;++c) s += W[k*32+c]*a[c];
    v = s;
  }
  dst[idx] = (_Float16)v;
}

// ---- pack second-layer weights (g1: 32 ntiles, gf: 2 ntiles) ----
__global__ void pack_wout_kernel(const float* __restrict__ g1_Wout, const float* __restrict__ gf_Wout,
                                 _Float16* __restrict__ dst1, _Float16* __restrict__ dstf){
  int idx = blockIdx.x*256 + threadIdx.x;   // 69632 total
  if (idx < 65536){
    int j = idx&7, lane=(idx>>3)&63, kk=(idx>>9)&3, nt=idx>>11;
    int k = kk*32 + (lane>>4)*8 + j;
    dst1[idx] = (_Float16)g1_Wout[k*512 + nt*16 + (lane&15)];
  } else {
    int i2 = idx - 65536;
    int j=i2&7, lane=(i2>>3)&63, kk=(i2>>9)&3, nt=i2>>11;
    int k = kk*32 + (lane>>4)*8 + j;
    dstf[i2] = (_Float16)gf_Wout[k*32 + nt*16 + (lane&15)];
  }
}

// ---- pack state-side fused weights: wstf [35][8][64][8] ----
__global__ void pack_wst_kernel(const float* __restrict__ hb_W, const float* __restrict__ wn_w,
                                const float* __restrict__ v1_w, _Float16* __restrict__ dst){
  int idx = blockIdx.x*256 + threadIdx.x;
  if (idx >= 35*4096) return;
  int j = idx&7, lane=(idx>>3)&63, kk=(idx>>9)&7, nt=idx>>12;
  int s = kk*32 + (lane>>4)*8 + j;
  int c = nt*16 + (lane&15);
  float v;
  if (c < 512)      v = hb_W[c*STATED + s];
  else if (c < 528) v = wn_w[(c-512)*STATED + s];
  else              v = v1_w[(c-528)*STATED + s];
  dst[idx] = (_Float16)v;
}

// ---- kernel 1: state projections via MFMA (b_all, dis, V) ----
__global__ __launch_bounds__(256) void st_kernel(
    const float* __restrict__ states,
    const _Float16* __restrict__ wstf,
    const float* __restrict__ hb_b, const float* __restrict__ wn_b,
    const float* __restrict__ v1_b, const float* __restrict__ v2_w,
    const float* __restrict__ v2_b,
    float* __restrict__ b_all, float* __restrict__ dis, float* __restrict__ vv){
  __shared__ float vh_s[16*32];
  const int t = threadIdx.x, w = t>>6, lane = t&63, lg = lane>>4, li = lane&15;
  const int b0 = blockIdx.x*16;
  const float* sp = states + (size_t)(b0+li)*STATED + lg*8;
  v8h ast[8];
  #pragma unroll
  for (int kk=0;kk<8;++kk){
    v4f f0 = *reinterpret_cast<const v4f*>(sp + kk*32);
    v4f f1 = *reinterpret_cast<const v4f*>(sp + kk*32 + 4);
    v8h h;
    #pragma unroll
    for (int jj=0;jj<4;++jj){ h[jj]=(_Float16)f0[jj]; h[4+jj]=(_Float16)f1[jj]; }
    ast[kk]=h;
  }
  for (int nt=w; nt<35; nt+=4){
    v4f d = {0.f,0.f,0.f,0.f};
    #pragma unroll
    for (int kk=0;kk<8;++kk){
      v8h bf = *reinterpret_cast<const v8h*>(wstf + (size_t)(((nt*8+kk)<<6)+lane)*8);
      d = MFMA32(ast[kk], bf, d);
    }
    int c = nt*16 + li;
    if (c < 512){
      float bias = hb_b[c];
      #pragma unroll
      for (int r=0;r<4;++r) b_all[(size_t)(b0+lg*4+r)*512 + c] = d[r]+bias;
    } else if (c < 528){
      float bias = wn_b[c-512];
      #pragma unroll
      for (int r=0;r<4;++r) dis[(b0+lg*4+r)*NAG + (c-512)] = fabsf(d[r]+bias);
    } else {
      float bias = v1_b[c-528];
      #pragma unroll
      for (int r=0;r<4;++r) vh_s[(lg*4+r)*32 + (c-528)] = fmaxf(d[r]+bias, 0.f);
    }
  }
  __syncthreads();
  if (t < 16){
    float s = v2_b[0];
    #pragma unroll
    for (int e=0;e<32;++e) s += vh_s[t*32+e]*v2_w[e];
    vv[b0+t] = s;
  }
}

// ---- kernel 2: dual-GAT, wave-owns-batch, pairwise joint out-GEMM, 6 blocks/CU ----
__global__ __launch_bounds__(256,6) void gat_kernel(
    const float* __restrict__ agent_qs,
    const float* __restrict__ obs_ls,
    const float* __restrict__ adj_ls,
    const _Float16* __restrict__ whf,    // [17][4][64][8]
    const _Float16* __restrict__ wo1f,   // [32][4][64][8]
    const _Float16* __restrict__ wodf,   // [2][4][64][8]
    const float* __restrict__ wa_g,      // [4][128]
    const float* __restrict__ b_all_ws,
    const float* __restrict__ dis_ws,
    const float* __restrict__ vv_ws,
    float* __restrict__ out){
  __shared__ __align__(16) _Float16 arena_h[4*SLOT_H];
  __shared__ __align__(8)  _Float16 adjh[4*256];
  __shared__ float qs_s[64];

  const int t = threadIdx.x, w = t>>6, lane = t&63, lg = lane>>4, li = lane&15;
  const int bb = blockIdx.x*4;
  const int b = bb + w;
  const int eh = w&1, pb = (w>>1)*2;
  const v4f ZERO4 = {0.f,0.f,0.f,0.f};

  // adj -> f16 (each thread writes its own wave's quarter: t*4 = w*256 + (t&63)*4)
  {
    float4 f = reinterpret_cast<const float4*>(adj_ls + (size_t)bb*256)[t];
    _Float16* ap = adjh + t*4;
    ap[0]=(_Float16)f.x; ap[1]=(_Float16)f.y; ap[2]=(_Float16)f.z; ap[3]=(_Float16)f.w;
  }
  if (t < 64) qs_s[t] = agent_qs[bb*NAG + t];

  _Float16* slot   = arena_h + w*SLOT_H;
  _Float16* att_h  = slot;            // [8][272] swizzled
  _Float16* uv_h   = slot + 2176;     // [8][32]
  _Float16* u2v2_h = slot + 2432;     // [4][16]
  _Float16* att2_h = slot + 2496;     // [2][16][18]
  const _Float16* adjw = adjh + w*256;

  // ---- P1: Wh = obs @ Wcat + fused u/v tile ----
  const float* ob = obs_ls + (size_t)b*(NAG*OBSD) + li*OBSD + lg*8;
  v8h aob[4];
  #pragma unroll
  for (int kk=0;kk<4;++kk){
    v4f f0 = *reinterpret_cast<const v4f*>(ob + kk*32);
    v4f f1 = *reinterpret_cast<const v4f*>(ob + kk*32 + 4);
    v8h h;
    #pragma unroll
    for (int jj=0;jj<4;++jj){ h[jj]=(_Float16)f0[jj]; h[4+jj]=(_Float16)f1[jj]; }
    aob[kk]=h;
  }
  v4h whB[16];
  #pragma unroll
  for (int nt=0;nt<16;++nt){
    v4f d = ZERO4;
    #pragma unroll
    for (int kk=0;kk<4;++kk){
      v8h bf = *reinterpret_cast<const v8h*>(whf + (size_t)(((nt*4+kk)<<6) + lane)*8);
      d = MFMA32(aob[kk], bf, d);
    }
    v4h hh;
    #pragma unroll
    for (int r=0;r<4;++r) hh[r]=(_Float16)d[r];
    whB[nt]=hh;
  }
  {
    v4f d = ZERO4;
    #pragma unroll
    for (int kk=0;kk<4;++kk){
      v8h bf = *reinterpret_cast<const v8h*>(whf + (size_t)(((64+kk)<<6) + lane)*8);
      d = MFMA32(aob[kk], bf, d);
    }
    #pragma unroll
    for (int r=0;r<4;++r)
      uv_h[(li>>1)*32 + (li&1)*16 + lg*4 + r] = (_Float16)d[r];
  }

  // ---- P2: att = softmax_i(mask(lrelu(u_i+v_j))); 2 cols/lane; swizzled u32 stores ----
  {
    int cc = lane*2;
    int g = cc>>4, j0 = cc&15;       // j0 even
    float vj0 = (float)uv_h[g*32+16+j0], vj1 = (float)uv_h[g*32+16+j0+1];
    float e0[16], e1[16];
    float m0=-INFINITY, m1=-INFINITY;
    #pragma unroll
    for (int i=0;i<16;++i){
      float u = (float)uv_h[g*32+i];
      union { unsigned u32; _Float16 h[2]; } aa;
      aa.u32 = *reinterpret_cast<const unsigned*>(adjw + i*16 + j0);
      float x0 = lrelu(u+vj0), x1 = lrelu(u+vj1);
      x0 = ((float)aa.h[0] > 0.f) ? x0 : NEGV;
      x1 = ((float)aa.h[1] > 0.f) ? x1 : NEGV;
      e0[i]=x0; e1[i]=x1;
      m0=fmaxf(m0,x0); m1=fmaxf(m1,x1);
    }
    float s0=0.f,s1=0.f;
    #pragma unroll
    for (int i=0;i<16;++i){ e0[i]=__expf(e0[i]-m0); e1[i]=__expf(e1[i]-m1); s0+=e0[i]; s1+=e1[i]; }
    float inv0=1.f/s0, inv1=1.f/s1;
    #pragma unroll
    for (int i=0;i<16;++i){
      union { unsigned u32; _Float16 h[2]; } pk;
      pk.h[0]=(_Float16)(e0[i]*inv0);
      pk.h[1]=(_Float16)(e1[i]*inv1);
      int blk = (j0>>2) ^ ((i>>2)&3);
      *reinterpret_cast<unsigned*>(&att_h[g*272 + i*16 + (blk<<2) + (j0&3)]) = pk.u32;
    }
  }

  // ---- P3: xcat = elu(att @ Wh); u2/v2 partials on the fly ----
  v4h xcB[16];
  float p2[4][4];
  #pragma unroll
  for (int k4=0;k4<4;++k4)
    #pragma unroll
    for (int r=0;r<4;++r) p2[k4][r]=0.f;
  {
    const int ablk = (lg ^ ((li>>2)&3)) << 2;
    #pragma unroll
    for (int g=0;g<8;++g){
      v4h afr = *reinterpret_cast<const v4h*>(&att_h[g*272 + li*16 + ablk]);
      int side = g>>2;
      #pragma unroll
      for (int h2=0;h2<2;++h2){
        int nt = g*2+h2;
        v4f d = ZERO4;
        d = MFMA16(afr, whB[nt], d);
        int cl = (nt - side*8)*16 + li;
        float wu = wa_g[side*256 + cl];
        float wv = wa_g[side*256 + 128 + cl];
        v4h hh;
        #pragma unroll
        for (int r=0;r<4;++r){
          float e = eluf(d[r]);
          hh[r]=(_Float16)e;
          p2[side*2][r]   += e*wu;
          p2[side*2+1][r] += e*wv;
        }
        xcB[nt]=hh;
      }
    }
  }
  #pragma unroll
  for (int off=1; off<16; off<<=1)
    #pragma unroll
    for (int k4=0;k4<4;++k4)
      #pragma unroll
      for (int r=0;r<4;++r) p2[k4][r] += __shfl_xor(p2[k4][r], off, 64);
  if (li==0){
    #pragma unroll
    for (int k4=0;k4<4;++k4)
      #pragma unroll
      for (int r=0;r<4;++r) u2v2_h[k4*16 + lg*4 + r] = (_Float16)p2[k4][r];
  }

  // ---- ATT2: both second-layer attentions for own batch ----
  if (lane < 32){
    int side = lane>>4, j = lane&15;
    float vj = (float)u2v2_h[side*32 + 16 + j];
    float ev[16]; float m=-INFINITY;
    #pragma unroll
    for (int i=0;i<16;++i){
      float x = lrelu((float)u2v2_h[side*32 + i] + vj);
      x = ((float)adjw[i*16+j] > 0.f) ? x : NEGV;
      ev[i]=x; m=fmaxf(m,x);
    }
    float ss=0.f;
    #pragma unroll
    for (int i=0;i<16;++i){ ev[i]=__expf(ev[i]-m); ss+=ev[i]; }
    float inv=1.f/ss;
    #pragma unroll
    for (int i=0;i<16;++i) att2_h[side*288 + j*18 + i] = (_Float16)(ev[i]*inv);
  }

  // ---- Z: z^T = xcat^T @ att2^T; g1 -> LDS head now, gf -> regs (write post-B2) ----
  v4h bat0, bat1;
  #pragma unroll
  for (int jj=0;jj<4;++jj){
    bat0[jj] = att2_h[(lg*4+jj)*18 + li];
    bat1[jj] = att2_h[288 + (lg*4+jj)*18 + li];
  }
  #pragma unroll
  for (int ct=0;ct<8;++ct){
    v4f zD = ZERO4;
    zD = MFMA16(xcB[ct], bat0, zD);
    int kk = ct>>1;
    int lp = li + 16*((ct&1)*2 + (lg>>1));
    _Float16* dst = slot + kk*512 + lp*8 + (lg&1)*4;
    union { unsigned u32; _Float16 h[2]; } q0,q1;
    q0.h[0]=(_Float16)zD[0]; q0.h[1]=(_Float16)zD[1];
    q1.h[0]=(_Float16)zD[2]; q1.h[1]=(_Float16)zD[3];
    *reinterpret_cast<unsigned*>(dst)   = q0.u32;
    *reinterpret_cast<unsigned*>(dst+2) = q1.u32;
  }
  unsigned qg0[8], qg1[8];
  #pragma unroll
  for (int ct=0;ct<8;++ct){
    v4f zD = ZERO4;
    zD = MFMA16(xcB[8+ct], bat1, zD);
    union { unsigned u32; _Float16 h[2]; } q0,q1;
    q0.h[0]=(_Float16)zD[0]; q0.h[1]=(_Float16)zD[1];
    q1.h[0]=(_Float16)zD[2]; q1.h[1]=(_Float16)zD[3];
    qg0[ct]=q0.u32; qg1[ct]=q1.u32;
  }
  __syncthreads();   // B1: all g1-zh ready

  // ---- az: g1 A-frags for the batch PAIR ----
  v8h az[2][4];
  #pragma unroll
  for (int bi=0;bi<2;++bi)
    #pragma unroll
    for (int kk=0;kk<4;++kk)
      az[bi][kk] = *reinterpret_cast<const v8h*>(arena_h + (pb+bi)*SLOT_H + kk*512 + lane*8);
  __syncthreads();   // B2: az reads done; heads reusable (wave-local)

  // gf-z -> own head, azf read (wave-local, in-order)
  #pragma unroll
  for (int ct=0;ct<8;++ct){
    int kk = ct>>1;
    int lp = li + 16*((ct&1)*2 + (lg>>1));
    _Float16* dst = slot + kk*512 + lp*8 + (lg&1)*4;
    *reinterpret_cast<unsigned*>(dst)   = qg0[ct];
    *reinterpret_cast<unsigned*>(dst+2) = qg1[ct];
  }
  v8h azf[4];
  #pragma unroll
  for (int kk=0;kk<4;++kk)
    azf[kk] = *reinterpret_cast<const v8h*>(slot + kk*512 + lane*8);
  __syncthreads();   // B2.5: all azf reads done before part overwrites heads

  // gf out-GEMM + epilogue -> hyp regs
  float hyp[2][4];
  #pragma unroll
  for (int nt2=0;nt2<2;++nt2){
    v4f d = ZERO4;
    #pragma unroll
    for (int kk=0;kk<4;++kk){
      v8h bf = *reinterpret_cast<const v8h*>(wodf + (size_t)(((nt2*4+kk)<<6)+lane)*8);
      d = MFMA32(azf[kk], bf, d);
    }
    float x[4];
    #pragma unroll
    for (int r=0;r<4;++r) x[r]=eluf(d[r]);
    float m = fmaxf(fmaxf(x[0],x[1]),fmaxf(x[2],x[3]));
    m = fmaxf(m, __shfl_xor(m,16,64));
    m = fmaxf(m, __shfl_xor(m,32,64));
    float s = __expf(x[0]-m)+__expf(x[1]-m)+__expf(x[2]-m)+__expf(x[3]-m);
    s += __shfl_xor(s,16,64);
    s += __shfl_xor(s,32,64);
    float ls = m + __logf(s);
    #pragma unroll
    for (int r=0;r<4;++r) hyp[nt2][r] = fabsf(x[r]-ls);
  }

  // g1 joint out-GEMM: 16 n (own eh) x 2 batches
  {
    float pa[2][4];
    #pragma unroll
    for (int bi=0;bi<2;++bi)
      #pragma unroll
      for (int r=0;r<4;++r) pa[bi][r]=0.f;
    #pragma unroll
    for (int n=0;n<16;++n){
      int nt = n*2 + eh;
      v8h bf[4];
      #pragma unroll
      for (int kk=0;kk<4;++kk)
        bf[kk] = *reinterpret_cast<const v8h*>(wo1f + (size_t)(((nt*4+kk)<<6)+lane)*8);
      #pragma unroll
      for (int bi=0;bi<2;++bi){
        v4f d = ZERO4;
        #pragma unroll
        for (int kk=0;kk<4;++kk) d = MFMA32(az[bi][kk], bf[kk], d);
        float x[4];
        #pragma unroll
        for (int r=0;r<4;++r) x[r]=eluf(d[r]);
        float m = fmaxf(fmaxf(x[0],x[1]),fmaxf(x[2],x[3]));
        m = fmaxf(m, __shfl_xor(m,16,64));
        m = fmaxf(m, __shfl_xor(m,32,64));
        float s = __expf(x[0]-m)+__expf(x[1]-m)+__expf(x[2]-m)+__expf(x[3]-m);
        s += __shfl_xor(s,16,64);
        s += __shfl_xor(s,32,64);
        float ls = m + __logf(s);
        float q = qs_s[(pb+bi)*16 + n];
        #pragma unroll
        for (int r=0;r<4;++r) pa[bi][r] += q*fabsf(x[r]-ls);
      }
    }
    // part[b][eh]: eh==1 -> slot head [0,1024)f; eh==0 -> [2048h..) as floats
    #pragma unroll
    for (int bi=0;bi<2;++bi){
      float* pdst = reinterpret_cast<float*>(arena_h + (pb+bi)*SLOT_H + (eh ? 0 : 2048));
      #pragma unroll
      for (int r=0;r<4;++r) pdst[(lg*4+r)*16 + li] = pa[bi][r];
    }
  }
  __syncthreads();   // B3: part ready

  // ---- final: hidden = elu(b_all + part) * hyp; wave-local reduce; out ----
  {
    const float* ph0 = reinterpret_cast<const float*>(slot + 2048);  // eh=0
    const float* ph1 = reinterpret_cast<const float*>(slot);         // eh=1
    const float* ba = b_all_ws + (size_t)b*512;
    float ps[4] = {0.f,0.f,0.f,0.f};
    #pragma unroll
    for (int nt2=0;nt2<2;++nt2){
      const float* ph = nt2 ? ph1 : ph0;
      #pragma unroll
      for (int r=0;r<4;++r){
        int i = lg*4+r;
        float hv = eluf(ba[i*32 + nt2*16 + li] + ph[i*16 + li]);
        ps[r] += hv * hyp[nt2][r];
      }
    }
    #pragma unroll
    for (int off=1; off<16; off<<=1)
      #pragma unroll
      for (int r=0;r<4;++r) ps[r] += __shfl_xor(ps[r], off, 64);
    float qp = 0.f;
    #pragma unroll
    for (int r=0;r<4;++r) qp += ps[r] * dis_ws[(size_t)b*NAG + lg*4 + r];
    qp += __shfl_xor(qp, 16, 64);
    qp += __shfl_xor(qp, 32, 64);
    if (lane == 0) out[b] = qp + vv_ws[b];
  }
}

extern "C" void kernel_launch(void* const* d_in, const int* in_sizes, int n_in,
                              void* d_out, int out_size, void* d_ws, size_t ws_size,
                              hipStream_t stream) {
  const float* agent_qs = (const float*)d_in[0];
  const float* states   = (const float*)d_in[1];
  const float* obs_ls   = (const float*)d_in[2];
  const float* adj_ls   = (const float*)d_in[3];
  const float* wn_w     = (const float*)d_in[4];
  const float* wn_b     = (const float*)d_in[5];
  const float* g1_Wh    = (const float*)d_in[6];
  const float* g1_ah    = (const float*)d_in[7];
  const float* g1_Wout  = (const float*)d_in[8];
  const float* g1_aout  = (const float*)d_in[9];
  const float* gf_Wh    = (const float*)d_in[10];
  const float* gf_ah    = (const float*)d_in[11];
  const float* gf_Wout  = (const float*)d_in[12];
  const float* gf_aout  = (const float*)d_in[13];
  const float* hb_W     = (const float*)d_in[14];
  const float* hb_b     = (const float*)d_in[15];
  const float* v1_w     = (const float*)d_in[16];
  const float* v1_b     = (const float*)d_in[17];
  const float* v2_w     = (const float*)d_in[18];
  const float* v2_b     = (const float*)d_in[19];

  float* ws    = (float*)d_ws;
  float* b_all = ws;                          // 8192*512
  float* dis   = b_all + (size_t)BTOT*512;    // 8192*16
  float* vvv   = dis + (size_t)BTOT*NAG;      // 8192
  float* wa    = vvv + BTOT;                  // 512
  _Float16* whf  = (_Float16*)(wa + 512);     // 34816 h
  _Float16* wo1f = whf + 34816;               // 65536 h
  _Float16* wodf = wo1f + 65536;              // 4096 h
  _Float16* wstf = wodf + 4096;               // 143360 h

  prep2_kernel<<<dim3(1), dim3(128), 0, stream>>>(g1_Wout, g1_aout, gf_Wout, gf_aout, wa);
  pack_wh_kernel<<<dim3(136), dim3(256), 0, stream>>>(g1_Wh, gf_Wh, g1_ah, gf_ah, whf);
  pack_wout_kernel<<<dim3(272), dim3(256), 0, stream>>>(g1_Wout, gf_Wout, wo1f, wodf);
  pack_wst_kernel<<<dim3(560), dim3(256), 0, stream>>>(hb_W, wn_w, v1_w, wstf);
  st_kernel<<<dim3(BTOT/16), dim3(256), 0, stream>>>(states, wstf, hb_b, wn_b, v1_b, v2_w, v2_b,
                                                     b_all, dis, vvv);
  gat_kernel<<<dim3(BTOT/4), dim3(256), 0, stream>>>(agent_qs, obs_ls, adj_ls,
                                                     whf, wo1f, wodf, wa,
                                                     b_all, dis, vvv, (float*)d_out);
}

// Round 7
// 125.312 us; speedup vs baseline: 2.9022x; 2.9022x over previous
//
#include <hip/hip_runtime.h>
#include <math.h>

#define NAG 16
#define OBSD 128
#define STATED 256
#define ALPHA 0.2f
#define NEGV -9.0e15f
#define BTOT 8192
#define SLOT_H 3072   // halves per wave slot

typedef _Float16 v4h __attribute__((ext_vector_type(4)));
typedef _Float16 v8h __attribute__((ext_vector_type(8)));
typedef float v4f __attribute__((ext_vector_type(4)));

__device__ __forceinline__ float lrelu(float x){ return x > 0.f ? x : ALPHA*x; }
__device__ __forceinline__ float eluf(float x){ return x > 0.f ? x : (__expf(x)-1.f); }

#define MFMA16(A,B,C) __builtin_amdgcn_mfma_f32_16x16x16f16((A),(B),(C),0,0,0)
#define MFMA32(A,B,C) __builtin_amdgcn_mfma_f32_16x16x32_f16((A),(B),(C),0,0,0)

// ---- prep2: wa[4][128] = Wout @ aout halves (g1 u/v, gf u/v) ----
__global__ void prep2_kernel(const float* __restrict__ g1_Wout, const float* __restrict__ g1_aout,
                             const float* __restrict__ gf_Wout, const float* __restrict__ gf_aout,
                             float* __restrict__ wa){
  int k = threadIdx.x;  // 128
  float su = 0.f, sv = 0.f;
  for (int c = 0; c < 512; ++c){
    float w = g1_Wout[k*512 + c];
    su += w * g1_aout[c];
    sv += w * g1_aout[512 + c];
  }
  wa[k] = su; wa[128 + k] = sv;
  float fu = 0.f, fv = 0.f;
  for (int c = 0; c < 32; ++c){
    float w = gf_Wout[k*32 + c];
    fu += w * gf_aout[c];
    fv += w * gf_aout[32 + c];
  }
  wa[256 + k] = fu; wa[384 + k] = fv;
}

// ---- pack first-layer weights + (W@a) u/v columns: whf [17][4][64][8] ----
__global__ void pack_wh_kernel(const float* __restrict__ g1_Wh, const float* __restrict__ gf_Wh,
                               const float* __restrict__ g1_ah, const float* __restrict__ gf_ah,
                               _Float16* __restrict__ dst){
  int idx = blockIdx.x*256 + threadIdx.x;   // 34816 total
  if (idx >= 17*2048) return;
  int j = idx & 7, lane = (idx>>3)&63, kk = (idx>>9)&3, nt = idx>>11;
  int k = kk*32 + (lane>>4)*8 + j;
  int li = lane & 15;
  float v;
  if (nt < 16){
    int g = nt>>1, c = (nt&1)*16 + li;
    v = (g<4) ? g1_Wh[(g*OBSD + k)*32 + c] : gf_Wh[((g-4)*OBSD + k)*32 + c];
  } else {
    int g = li>>1, half = li&1;
    const float* W = (g<4)? (g1_Wh + g*OBSD*32) : (gf_Wh + (g-4)*OBSD*32);
    const float* a = ((g<4)? (g1_ah + g*64) : (gf_ah + (g-4)*64)) + half*32;
    float s = 0.f;
    for (int c=0;c<32;++c) s += W[k*32+c]*a[c];
    v = s;
  }
  dst[idx] = (_Float16)v;
}

// ---- pack second-layer weights (g1: 32 ntiles, gf: 2 ntiles) ----
__global__ void pack_wout_kernel(const float* __restrict__ g1_Wout, const float* __restrict__ gf_Wout,
                                 _Float16* __restrict__ dst1, _Float16* __restrict__ dstf){
  int idx = blockIdx.x*256 + threadIdx.x;   // 69632 total
  if (idx < 65536){
    int j = idx&7, lane=(idx>>3)&63, kk=(idx>>9)&3, nt=idx>>11;
    int k = kk*32 + (lane>>4)*8 + j;
    dst1[idx] = (_Float16)g1_Wout[k*512 + nt*16 + (lane&15)];
  } else {
    int i2 = idx - 65536;
    int j=i2&7, lane=(i2>>3)&63, kk=(i2>>9)&3, nt=i2>>11;
    int k = kk*32 + (lane>>4)*8 + j;
    dstf[i2] = (_Float16)gf_Wout[k*32 + nt*16 + (lane&15)];
  }
}

// ---- pack state-side fused weights: wstf [35][8][64][8] ----
__global__ void pack_wst_kernel(const float* __restrict__ hb_W, const float* __restrict__ wn_w,
                                const float* __restrict__ v1_w, _Float16* __restrict__ dst){
  int idx = blockIdx.x*256 + threadIdx.x;
  if (idx >= 35*4096) return;
  int j = idx&7, lane=(idx>>3)&63, kk=(idx>>9)&7, nt=idx>>12;
  int s = kk*32 + (lane>>4)*8 + j;
  int c = nt*16 + (lane&15);
  float v;
  if (c < 512)      v = hb_W[c*STATED + s];
  else if (c < 528) v = wn_w[(c-512)*STATED + s];
  else              v = v1_w[(c-528)*STATED + s];
  dst[idx] = (_Float16)v;
}

// ---- kernel 1: state projections via MFMA (b_all, dis, V) ----
__global__ __launch_bounds__(256) void st_kernel(
    const float* __restrict__ states,
    const _Float16* __restrict__ wstf,
    const float* __restrict__ hb_b, const float* __restrict__ wn_b,
    const float* __restrict__ v1_b, const float* __restrict__ v2_w,
    const float* __restrict__ v2_b,
    float* __restrict__ b_all, float* __restrict__ dis, float* __restrict__ vv){
  __shared__ float vh_s[16*32];
  const int t = threadIdx.x, w = t>>6, lane = t&63, lg = lane>>4, li = lane&15;
  const int b0 = blockIdx.x*16;
  const float* sp = states + (size_t)(b0+li)*STATED + lg*8;
  v8h ast[8];
  #pragma unroll
  for (int kk=0;kk<8;++kk){
    v4f f0 = *reinterpret_cast<const v4f*>(sp + kk*32);
    v4f f1 = *reinterpret_cast<const v4f*>(sp + kk*32 + 4);
    v8h h;
    #pragma unroll
    for (int jj=0;jj<4;++jj){ h[jj]=(_Float16)f0[jj]; h[4+jj]=(_Float16)f1[jj]; }
    ast[kk]=h;
  }
  for (int nt=w; nt<35; nt+=4){
    v4f d = {0.f,0.f,0.f,0.f};
    #pragma unroll
    for (int kk=0;kk<8;++kk){
      v8h bf = *reinterpret_cast<const v8h*>(wstf + (size_t)(((nt*8+kk)<<6)+lane)*8);
      d = MFMA32(ast[kk], bf, d);
    }
    int c = nt*16 + li;
    if (c < 512){
      float bias = hb_b[c];
      #pragma unroll
      for (int r=0;r<4;++r) b_all[(size_t)(b0+lg*4+r)*512 + c] = d[r]+bias;
    } else if (c < 528){
      float bias = wn_b[c-512];
      #pragma unroll
      for (int r=0;r<4;++r) dis[(b0+lg*4+r)*NAG + (c-512)] = fabsf(d[r]+bias);
    } else {
      float bias = v1_b[c-528];
      #pragma unroll
      for (int r=0;r<4;++r) vh_s[(lg*4+r)*32 + (c-528)] = fmaxf(d[r]+bias, 0.f);
    }
  }
  __syncthreads();
  if (t < 16){
    float s = v2_b[0];
    #pragma unroll
    for (int e=0;e<32;++e) s += vh_s[t*32+e]*v2_w[e];
    vv[b0+t] = s;
  }
}

// ---- kernel 2: dual-GAT, wave-owns-batch, pairwise joint out-GEMM ----
__global__ __launch_bounds__(256,4) void gat_kernel(
    const float* __restrict__ agent_qs,
    const float* __restrict__ obs_ls,
    const float* __restrict__ adj_ls,
    const _Float16* __restrict__ whf,    // [17][4][64][8]
    const _Float16* __restrict__ wo1f,   // [32][4][64][8]
    const _Float16* __restrict__ wodf,   // [2][4][64][8]
    const float* __restrict__ wa_g,      // [4][128]
    const float* __restrict__ b_all_ws,
    const float* __restrict__ dis_ws,
    const float* __restrict__ vv_ws,
    float* __restrict__ out){
  __shared__ __align__(16) _Float16 arena_h[4*SLOT_H];
  __shared__ __align__(8)  _Float16 adjh[4*256];
  __shared__ float qs_s[64];

  const int t = threadIdx.x, w = t>>6, lane = t&63, lg = lane>>4, li = lane&15;
  const int bb = blockIdx.x*4;
  const int b = bb + w;
  const int eh = w&1, pb = (w>>1)*2;
  const v4f ZERO4 = {0.f,0.f,0.f,0.f};

  // adj -> f16 (each thread writes its own wave's quarter: t*4 = w*256 + (t&63)*4)
  {
    float4 f = reinterpret_cast<const float4*>(adj_ls + (size_t)bb*256)[t];
    _Float16* ap = adjh + t*4;
    ap[0]=(_Float16)f.x; ap[1]=(_Float16)f.y; ap[2]=(_Float16)f.z; ap[3]=(_Float16)f.w;
  }
  if (t < 64) qs_s[t] = agent_qs[bb*NAG + t];

  _Float16* slot   = arena_h + w*SLOT_H;
  _Float16* att_h  = slot;            // [8][272] swizzled
  _Float16* uv_h   = slot + 2176;     // [8][32]
  _Float16* u2v2_h = slot + 2432;     // [4][16]
  _Float16* att2_h = slot + 2496;     // [2][16][18]
  const _Float16* adjw = adjh + w*256;

  // ---- P1: Wh = obs @ Wcat + fused u/v tile ----
  const float* ob = obs_ls + (size_t)b*(NAG*OBSD) + li*OBSD + lg*8;
  v8h aob[4];
  #pragma unroll
  for (int kk=0;kk<4;++kk){
    v4f f0 = *reinterpret_cast<const v4f*>(ob + kk*32);
    v4f f1 = *reinterpret_cast<const v4f*>(ob + kk*32 + 4);
    v8h h;
    #pragma unroll
    for (int jj=0;jj<4;++jj){ h[jj]=(_Float16)f0[jj]; h[4+jj]=(_Float16)f1[jj]; }
    aob[kk]=h;
  }
  v4h whB[16];
  #pragma unroll
  for (int nt=0;nt<16;++nt){
    v4f d = ZERO4;
    #pragma unroll
    for (int kk=0;kk<4;++kk){
      v8h bf = *reinterpret_cast<const v8h*>(whf + (size_t)(((nt*4+kk)<<6) + lane)*8);
      d = MFMA32(aob[kk], bf, d);
    }
    v4h hh;
    #pragma unroll
    for (int r=0;r<4;++r) hh[r]=(_Float16)d[r];
    whB[nt]=hh;
  }
  {
    v4f d = ZERO4;
    #pragma unroll
    for (int kk=0;kk<4;++kk){
      v8h bf = *reinterpret_cast<const v8h*>(whf + (size_t)(((64+kk)<<6) + lane)*8);
      d = MFMA32(aob[kk], bf, d);
    }
    #pragma unroll
    for (int r=0;r<4;++r)
      uv_h[(li>>1)*32 + (li&1)*16 + lg*4 + r] = (_Float16)d[r];
  }

  // ---- P2: att = softmax_i(mask(lrelu(u_i+v_j))); 2 cols/lane; swizzled u32 stores ----
  {
    int cc = lane*2;
    int g = cc>>4, j0 = cc&15;       // j0 even
    float vj0 = (float)uv_h[g*32+16+j0], vj1 = (float)uv_h[g*32+16+j0+1];
    float e0[16], e1[16];
    float m0=-INFINITY, m1=-INFINITY;
    #pragma unroll
    for (int i=0;i<16;++i){
      float u = (float)uv_h[g*32+i];
      union { unsigned u32; _Float16 h[2]; } aa;
      aa.u32 = *reinterpret_cast<const unsigned*>(adjw + i*16 + j0);
      float x0 = lrelu(u+vj0), x1 = lrelu(u+vj1);
      x0 = ((float)aa.h[0] > 0.f) ? x0 : NEGV;
      x1 = ((float)aa.h[1] > 0.f) ? x1 : NEGV;
      e0[i]=x0; e1[i]=x1;
      m0=fmaxf(m0,x0); m1=fmaxf(m1,x1);
    }
    float s0=0.f,s1=0.f;
    #pragma unroll
    for (int i=0;i<16;++i){ e0[i]=__expf(e0[i]-m0); e1[i]=__expf(e1[i]-m1); s0+=e0[i]; s1+=e1[i]; }
    float inv0=1.f/s0, inv1=1.f/s1;
    #pragma unroll
    for (int i=0;i<16;++i){
      union { unsigned u32; _Float16 h[2]; } pk;
      pk.h[0]=(_Float16)(e0[i]*inv0);
      pk.h[1]=(_Float16)(e1[i]*inv1);
      int blk = (j0>>2) ^ ((i>>2)&3);
      *reinterpret_cast<unsigned*>(&att_h[g*272 + i*16 + (blk<<2) + (j0&3)]) = pk.u32;
    }
  }

  // ---- P3: xcat = elu(att @ Wh); u2/v2 partials on the fly ----
  v4h xcB[16];
  float p2[4][4];
  #pragma unroll
  for (int k4=0;k4<4;++k4)
    #pragma unroll
    for (int r=0;r<4;++r) p2[k4][r]=0.f;
  {
    const int ablk = (lg ^ ((li>>2)&3)) << 2;
    #pragma unroll
    for (int g=0;g<8;++g){
      v4h afr = *reinterpret_cast<const v4h*>(&att_h[g*272 + li*16 + ablk]);
      int side = g>>2;
      #pragma unroll
      for (int h2=0;h2<2;++h2){
        int nt = g*2+h2;
        v4f d = ZERO4;
        d = MFMA16(afr, whB[nt], d);
        int cl = (nt - side*8)*16 + li;
        float wu = wa_g[side*256 + cl];
        float wv = wa_g[side*256 + 128 + cl];
        v4h hh;
        #pragma unroll
        for (int r=0;r<4;++r){
          float e = eluf(d[r]);
          hh[r]=(_Float16)e;
          p2[side*2][r]   += e*wu;
          p2[side*2+1][r] += e*wv;
        }
        xcB[nt]=hh;
      }
    }
  }
  #pragma unroll
  for (int off=1; off<16; off<<=1)
    #pragma unroll
    for (int k4=0;k4<4;++k4)
      #pragma unroll
      for (int r=0;r<4;++r) p2[k4][r] += __shfl_xor(p2[k4][r], off, 64);
  if (li==0){
    #pragma unroll
    for (int k4=0;k4<4;++k4)
      #pragma unroll
      for (int r=0;r<4;++r) u2v2_h[k4*16 + lg*4 + r] = (_Float16)p2[k4][r];
  }

  // ---- ATT2: both second-layer attentions for own batch ----
  if (lane < 32){
    int side = lane>>4, j = lane&15;
    float vj = (float)u2v2_h[side*32 + 16 + j];
    float ev[16]; float m=-INFINITY;
    #pragma unroll
    for (int i=0;i<16;++i){
      float x = lrelu((float)u2v2_h[side*32 + i] + vj);
      x = ((float)adjw[i*16+j] > 0.f) ? x : NEGV;
      ev[i]=x; m=fmaxf(m,x);
    }
    float ss=0.f;
    #pragma unroll
    for (int i=0;i<16;++i){ ev[i]=__expf(ev[i]-m); ss+=ev[i]; }
    float inv=1.f/ss;
    #pragma unroll
    for (int i=0;i<16;++i) att2_h[side*288 + j*18 + i] = (_Float16)(ev[i]*inv);
  }

  // ---- Z: z^T = xcat^T @ att2^T; g1 -> LDS head now, gf -> regs (write post-B2) ----
  v4h bat0, bat1;
  #pragma unroll
  for (int jj=0;jj<4;++jj){
    bat0[jj] = att2_h[(lg*4+jj)*18 + li];
    bat1[jj] = att2_h[288 + (lg*4+jj)*18 + li];
  }
  #pragma unroll
  for (int ct=0;ct<8;++ct){
    v4f zD = ZERO4;
    zD = MFMA16(xcB[ct], bat0, zD);
    int kk = ct>>1;
    int lp = li + 16*((ct&1)*2 + (lg>>1));
    _Float16* dst = slot + kk*512 + lp*8 + (lg&1)*4;
    union { unsigned u32; _Float16 h[2]; } q0,q1;
    q0.h[0]=(_Float16)zD[0]; q0.h[1]=(_Float16)zD[1];
    q1.h[0]=(_Float16)zD[2]; q1.h[1]=(_Float16)zD[3];
    *reinterpret_cast<unsigned*>(dst)   = q0.u32;
    *reinterpret_cast<unsigned*>(dst+2) = q1.u32;
  }
  unsigned qg0[8], qg1[8];
  #pragma unroll
  for (int ct=0;ct<8;++ct){
    v4f zD = ZERO4;
    zD = MFMA16(xcB[8+ct], bat1, zD);
    union { unsigned u32; _Float16 h[2]; } q0,q1;
    q0.h[0]=(_Float16)zD[0]; q0.h[1]=(_Float16)zD[1];
    q1.h[0]=(_Float16)zD[2]; q1.h[1]=(_Float16)zD[3];
    qg0[ct]=q0.u32; qg1[ct]=q1.u32;
  }
  __syncthreads();   // B1: all g1-zh ready

  // ---- az: g1 A-frags for the batch PAIR ----
  v8h az[2][4];
  #pragma unroll
  for (int bi=0;bi<2;++bi)
    #pragma unroll
    for (int kk=0;kk<4;++kk)
      az[bi][kk] = *reinterpret_cast<const v8h*>(arena_h + (pb+bi)*SLOT_H + kk*512 + lane*8);
  __syncthreads();   // B2: az reads done; heads reusable (wave-local)

  // gf-z -> own head, azf read (wave-local, in-order)
  #pragma unroll
  for (int ct=0;ct<8;++ct){
    int kk = ct>>1;
    int lp = li + 16*((ct&1)*2 + (lg>>1));
    _Float16* dst = slot + kk*512 + lp*8 + (lg&1)*4;
    *reinterpret_cast<unsigned*>(dst)   = qg0[ct];
    *reinterpret_cast<unsigned*>(dst+2) = qg1[ct];
  }
  v8h azf[4];
  #pragma unroll
  for (int kk=0;kk<4;++kk)
    azf[kk] = *reinterpret_cast<const v8h*>(slot + kk*512 + lane*8);
  __syncthreads();   // B2.5: all azf reads done before part overwrites heads

  // gf out-GEMM + epilogue -> hyp regs
  float hyp[2][4];
  #pragma unroll
  for (int nt2=0;nt2<2;++nt2){
    v4f d = ZERO4;
    #pragma unroll
    for (int kk=0;kk<4;++kk){
      v8h bf = *reinterpret_cast<const v8h*>(wodf + (size_t)(((nt2*4+kk)<<6)+lane)*8);
      d = MFMA32(azf[kk], bf, d);
    }
    float x[4];
    #pragma unroll
    for (int r=0;r<4;++r) x[r]=eluf(d[r]);
    float m = fmaxf(fmaxf(x[0],x[1]),fmaxf(x[2],x[3]));
    m = fmaxf(m, __shfl_xor(m,16,64));
    m = fmaxf(m, __shfl_xor(m,32,64));
    float s = __expf(x[0]-m)+__expf(x[1]-m)+__expf(x[2]-m)+__expf(x[3]-m);
    s += __shfl_xor(s,16,64);
    s += __shfl_xor(s,32,64);
    float ls = m + __logf(s);
    #pragma unroll
    for (int r=0;r<4;++r) hyp[nt2][r] = fabsf(x[r]-ls);
  }

  // g1 joint out-GEMM: 16 n (own eh) x 2 batches
  {
    float pa[2][4];
    #pragma unroll
    for (int bi=0;bi<2;++bi)
      #pragma unroll
      for (int r=0;r<4;++r) pa[bi][r]=0.f;
    #pragma unroll
    for (int n=0;n<16;++n){
      int nt = n*2 + eh;
      v8h bf[4];
      #pragma unroll
      for (int kk=0;kk<4;++kk)
        bf[kk] = *reinterpret_cast<const v8h*>(wo1f + (size_t)(((nt*4+kk)<<6)+lane)*8);
      #pragma unroll
      for (int bi=0;bi<2;++bi){
        v4f d = ZERO4;
        #pragma unroll
        for (int kk=0;kk<4;++kk) d = MFMA32(az[bi][kk], bf[kk], d);
        float x[4];
        #pragma unroll
        for (int r=0;r<4;++r) x[r]=eluf(d[r]);
        float m = fmaxf(fmaxf(x[0],x[1]),fmaxf(x[2],x[3]));
        m = fmaxf(m, __shfl_xor(m,16,64));
        m = fmaxf(m, __shfl_xor(m,32,64));
        float s = __expf(x[0]-m)+__expf(x[1]-m)+__expf(x[2]-m)+__expf(x[3]-m);
        s += __shfl_xor(s,16,64);
        s += __shfl_xor(s,32,64);
        float ls = m + __logf(s);
        float q = qs_s[(pb+bi)*16 + n];
        #pragma unroll
        for (int r=0;r<4;++r) pa[bi][r] += q*fabsf(x[r]-ls);
      }
    }
    // part[b][eh]: eh==1 -> slot head [0,1024)f; eh==0 -> [2048h..) as floats
    #pragma unroll
    for (int bi=0;bi<2;++bi){
      float* pdst = reinterpret_cast<float*>(arena_h + (pb+bi)*SLOT_H + (eh ? 0 : 2048));
      #pragma unroll
      for (int r=0;r<4;++r) pdst[(lg*4+r)*16 + li] = pa[bi][r];
    }
  }
  __syncthreads();   // B3: part ready

  // ---- final: hidden = elu(b_all + part) * hyp; wave-local reduce; out ----
  {
    const float* ph0 = reinterpret_cast<const float*>(slot + 2048);  // eh=0
    const float* ph1 = reinterpret_cast<const float*>(slot);         // eh=1
    const float* ba = b_all_ws + (size_t)b*512;
    float ps[4] = {0.f,0.f,0.f,0.f};
    #pragma unroll
    for (int nt2=0;nt2<2;++nt2){
      const float* ph = nt2 ? ph1 : ph0;
      #pragma unroll
      for (int r=0;r<4;++r){
        int i = lg*4+r;
        float hv = eluf(ba[i*32 + nt2*16 + li] + ph[i*16 + li]);
        ps[r] += hv * hyp[nt2][r];
      }
    }
    #pragma unroll
    for (int off=1; off<16; off<<=1)
      #pragma unroll
      for (int r=0;r<4;++r) ps[r] += __shfl_xor(ps[r], off, 64);
    float qp = 0.f;
    #pragma unroll
    for (int r=0;r<4;++r) qp += ps[r] * dis_ws[(size_t)b*NAG + lg*4 + r];
    qp += __shfl_xor(qp, 16, 64);
    qp += __shfl_xor(qp, 32, 64);
    if (lane == 0) out[b] = qp + vv_ws[b];
  }
}

extern "C" void kernel_launch(void* const* d_in, const int* in_sizes, int n_in,
                              void* d_out, int out_size, void* d_ws, size_t ws_size,
                              hipStream_t stream) {
  const float* agent_qs = (const float*)d_in[0];
  const float* states   = (const float*)d_in[1];
  const float* obs_ls   = (const float*)d_in[2];
  const float* adj_ls   = (const float*)d_in[3];
  const float* wn_w     = (const float*)d_in[4];
  const float* wn_b     = (const float*)d_in[5];
  const float* g1_Wh    = (const float*)d_in[6];
  const float* g1_ah    = (const float*)d_in[7];
  const float* g1_Wout  = (const float*)d_in[8];
  const float* g1_aout  = (const float*)d_in[9];
  const float* gf_Wh    = (const float*)d_in[10];
  const float* gf_ah    = (const float*)d_in[11];
  const float* gf_Wout  = (const float*)d_in[12];
  const float* gf_aout  = (const float*)d_in[13];
  const float* hb_W     = (const float*)d_in[14];
  const float* hb_b     = (const float*)d_in[15];
  const float* v1_w     = (const float*)d_in[16];
  const float* v1_b     = (const float*)d_in[17];
  const float* v2_w     = (const float*)d_in[18];
  const float* v2_b     = (const float*)d_in[19];

  float* ws    = (float*)d_ws;
  float* b_all = ws;                          // 8192*512
  float* dis   = b_all + (size_t)BTOT*512;    // 8192*16
  float* vvv   = dis + (size_t)BTOT*NAG;      // 8192
  float* wa    = vvv + BTOT;                  // 512
  _Float16* whf  = (_Float16*)(wa + 512);     // 34816 h
  _Float16* wo1f = whf + 34816;               // 65536 h
  _Float16* wodf = wo1f + 65536;              // 4096 h
  _Float16* wstf = wodf + 4096;               // 143360 h

  prep2_kernel<<<dim3(1), dim3(128), 0, stream>>>(g1_Wout, g1_aout, gf_Wout, gf_aout, wa);
  pack_wh_kernel<<<dim3(136), dim3(256), 0, stream>>>(g1_Wh, gf_Wh, g1_ah, gf_ah, whf);
  pack_wout_kernel<<<dim3(272), dim3(256), 0, stream>>>(g1_Wout, gf_Wout, wo1f, wodf);
  pack_wst_kernel<<<dim3(560), dim3(256), 0, stream>>>(hb_W, wn_w, v1_w, wstf);
  st_kernel<<<dim3(BTOT/16), dim3(256), 0, stream>>>(states, wstf, hb_b, wn_b, v1_b, v2_w, v2_b,
                                                     b_all, dis, vvv);
  gat_kernel<<<dim3(BTOT/4), dim3(256), 0, stream>>>(agent_qs, obs_ls, adj_ls,
                                                     whf, wo1f, wodf, wa,
                                                     b_all, dis, vvv, (float*)d_out);
}